// Round 4
// baseline (448.756 us; speedup 1.0000x reference)
//
#include <hip/hip_runtime.h>
#include <math.h>

// DigitCaps dynamic routing. B=512, I=1152, K=8, C=10, D=16, 3 iters.
//
// R5 structure: materialize bf16 u_hat (189 MB) in ws; each routing pass
// streams it once; softmax fully in-register.
// R7 POST-MORTEM: forcing launch_bounds(256,6) on producer -> allocator gave
// VGPR 40 (< ~56 live) -> 1.2 GB scratch. Never force far below natural need.
// R8 POST-MORTEM: grid 1536 at 4 resident blocks/CU = 1.5 dispatch rounds.
// R9 POST-MORTEM: grid 1024 = only 4 blocks/CU EXIST -> 50% occupancy ceiling.
//   launch_bounds only caps the allocator; RESIDENCY comes from VGPR count.
//   VGPR=64 sits exactly at the 8-waves/SIMD tier (cliff at 64/128/256).
// R10: give the HW 8 blocks/CU worth of blocks (grid 2048):
//  - producer: K1_CH 64 (18 i/chunk), launch_bounds UNCHANGED (256,4) ->
//    VGPR stays 64, HW residency 8 blocks/CU.
//  - route3: register-lean rewrite (no prefetch pair; unpack-in-place so
//    packed regs die; peak ~58 VGPR) + launch_bounds(256,8) cap 64,
//    K2_CH 16 (72 i/wave), grid 2048. TLP (8 waves/SIMD) hides HBM latency.

#define UHQ 40          // ushort4 quads per (b,i) row (160 bf16 elems)
#define K1_CH 64        // producer i-chunks (18 i each), 4 b per wave
#define K2_CH 16        // route i-chunks per b (72 i each)

__device__ __forceinline__ float dot8(const float4 w0, const float4 w1,
                                      const float4 ua, const float4 ub) {
    return w0.x*ua.x + w0.y*ua.y + w0.z*ua.z + w0.w*ua.w
         + w1.x*ub.x + w1.y*ub.y + w1.z*ub.z + w1.w*ub.w;
}

__device__ __forceinline__ unsigned short bf16_rn(float x) {
    unsigned u = __float_as_uint(x);
    u += 0x7FFFu + ((u >> 16) & 1u);
    return (unsigned short)(u >> 16);
}
__device__ __forceinline__ float bf16_lo(unsigned p) {   // low bf16 of packed pair
    return __uint_as_float(p << 16);
}
__device__ __forceinline__ float bf16_hi(unsigned p) {   // high bf16 of packed pair
    return __uint_as_float(p & 0xFFFF0000u);
}

// ---------------- W transpose: W[i][c][d][k] -> W_t[i][j][q] (float4 units) ----------------
__global__ void transpose_W(const float4* __restrict__ W4, float4* __restrict__ Wt4)
{
    int tid = blockIdx.x * 256 + threadIdx.x;
    if (tid >= 1152 * 320) return;
    int i = tid / 320, r = tid - i * 320;
    int q = r >> 3, j = r & 7;
    Wt4[i * 320 + j * 40 + q] = W4[tid];   // read coalesced, scatter within 5 KB row
}

// ---------------- Producer (coalesced W_t): u_hat bf16 + fused pass-0 sum ----------------
// (256,4): allocator untouched -> VGPR=64 (no spill), which is exactly the
// 8-waves/SIMD residency tier. Grid 2048 = 8 blocks/CU worth: one full round.
__global__ __launch_bounds__(256, 4)
void produce_uhat_t(const float* __restrict__ u, const float* __restrict__ Wt,
                    unsigned short* __restrict__ uhat_h, float* __restrict__ s0)
{
    const int t = threadIdx.x, lane = t & 63, wv = t >> 6;
    const int gid = blockIdx.x * 4 + wv;
    const int bq  = gid / K1_CH;          // 0..127
    const int ch  = gid - bq * K1_CH;     // 0..63
    const int b0  = bq * 4;
    const int i0  = ch * 18;
    const int q   = lane;
    const bool act = (q < UHQ);

    float4 acc[4];
    #pragma unroll
    for (int bb = 0; bb < 4; ++bb) acc[bb] = make_float4(0.f, 0.f, 0.f, 0.f);

    for (int ii = 0; ii < 18; ++ii) {
        const int i = i0 + ii;
        float4 w4[8];
        if (act) {
            const float4* wb = (const float4*)(Wt + (size_t)i * 1280);
            #pragma unroll
            for (int j = 0; j < 8; ++j) w4[j] = wb[j * 40 + q];   // 640 B contiguous
        }
        #pragma unroll
        for (int bb = 0; bb < 4; ++bb) {
            const int b = b0 + bb;
            const float4* up = (const float4*)(u + ((size_t)b * 1152 + i) * 8);
            const float4 ua = up[0], ub = up[1];   // wave-uniform broadcast
            if (act) {
                float4 uh;
                uh.x = dot8(w4[0], w4[1], ua, ub);
                uh.y = dot8(w4[2], w4[3], ua, ub);
                uh.z = dot8(w4[4], w4[5], ua, ub);
                uh.w = dot8(w4[6], w4[7], ua, ub);
                acc[bb].x += uh.x; acc[bb].y += uh.y;
                acc[bb].z += uh.z; acc[bb].w += uh.w;
                ushort4 h;
                h.x = bf16_rn(uh.x); h.y = bf16_rn(uh.y);
                h.z = bf16_rn(uh.z); h.w = bf16_rn(uh.w);
                ((ushort4*)uhat_h)[((size_t)b * 1152 + i) * UHQ + q] = h;
            }
        }
    }
    if (act) {
#if defined(__HIP_DEVICE_COMPILE__)
        #pragma unroll
        for (int bb = 0; bb < 4; ++bb) {
            float* sp = s0 + (size_t)(b0 + bb) * 160 + q * 4;
            unsafeAtomicAdd(sp + 0, acc[bb].x);
            unsafeAtomicAdd(sp + 1, acc[bb].y);
            unsafeAtomicAdd(sp + 2, acc[bb].z);
            unsafeAtomicAdd(sp + 3, acc[bb].w);
        }
#endif
    }
}

// ---------------- Producer fallback (divergent W, no W_t buffer) ----------------
__global__ __launch_bounds__(256, 4)
void produce_uhat_div(const float* __restrict__ u, const float* __restrict__ W,
                      unsigned short* __restrict__ uhat_h, float* __restrict__ s0)
{
    const int t = threadIdx.x, lane = t & 63, wv = t >> 6;
    const int gid = blockIdx.x * 4 + wv;
    const int bq  = gid / K1_CH;
    const int ch  = gid - bq * K1_CH;
    const int b0  = bq * 4;
    const int i0  = ch * 18;
    const int q   = lane;
    const bool act = (q < UHQ);

    float4 acc[4];
    #pragma unroll
    for (int bb = 0; bb < 4; ++bb) acc[bb] = make_float4(0.f, 0.f, 0.f, 0.f);

    for (int ii = 0; ii < 18; ++ii) {
        const int i = i0 + ii;
        float4 w4[8];
        if (act) {
            const float4* wp = (const float4*)(W + (size_t)i * 1280 + q * 32);
            #pragma unroll
            for (int j = 0; j < 8; ++j) w4[j] = wp[j];
        }
        #pragma unroll
        for (int bb = 0; bb < 4; ++bb) {
            const int b = b0 + bb;
            const float4* up = (const float4*)(u + ((size_t)b * 1152 + i) * 8);
            const float4 ua = up[0], ub = up[1];
            if (act) {
                float4 uh;
                uh.x = dot8(w4[0], w4[1], ua, ub);
                uh.y = dot8(w4[2], w4[3], ua, ub);
                uh.z = dot8(w4[4], w4[5], ua, ub);
                uh.w = dot8(w4[6], w4[7], ua, ub);
                acc[bb].x += uh.x; acc[bb].y += uh.y;
                acc[bb].z += uh.z; acc[bb].w += uh.w;
                ushort4 h;
                h.x = bf16_rn(uh.x); h.y = bf16_rn(uh.y);
                h.z = bf16_rn(uh.z); h.w = bf16_rn(uh.w);
                ((ushort4*)uhat_h)[((size_t)b * 1152 + i) * UHQ + q] = h;
            }
        }
    }
    if (act) {
#if defined(__HIP_DEVICE_COMPILE__)
        #pragma unroll
        for (int bb = 0; bb < 4; ++bb) {
            float* sp = s0 + (size_t)(b0 + bb) * 160 + q * 4;
            unsafeAtomicAdd(sp + 0, acc[bb].x);
            unsafeAtomicAdd(sp + 1, acc[bb].y);
            unsafeAtomicAdd(sp + 2, acc[bb].z);
            unsafeAtomicAdd(sp + 3, acc[bb].w);
        }
#endif
    }
}

// ---------------- Routing pass v3: register-lean, 8 waves/SIMD ----------------
// lane = (i_sub 0..3, c 0..15); wave does 4 rows/step, 72 i total (18 steps).
// Packed words unpacked in place (die immediately): peak ~58 VGPR -> fits the
// 64-VGPR/8-wave tier. Latency hidden by TLP, not ILP. #pragma unroll 1 pins
// register pressure.
template <int PASS>
__global__ __launch_bounds__(256, 8)
void route3(const unsigned short* __restrict__ uhat_h,
            const float* __restrict__ v0g, const float* __restrict__ v1g,
            float* __restrict__ sg)
{
    const int t = threadIdx.x, lane = t & 63, wv = t >> 6;
    const int gid  = blockIdx.x * 4 + wv;
    const int b    = gid >> 4;            // 0..511
    const int ch   = gid & 15;            // 0..15
    const int i0   = ch * 72;
    const int isub = lane >> 4;           // 0..3
    const int c    = lane & 15;           // 0..15, valid c<10
    const bool act = (c < 10);
    const int cc   = act ? c : 9;         // clamp for v load

    // v[b, cc, 0..15]  (f32)
    float v[16];
    {
        const float4* vp = (const float4*)(v0g + ((size_t)b * 10 + cc) * 16);
        float4 a0 = vp[0], a1 = vp[1], a2 = vp[2], a3 = vp[3];
        if (PASS == 2) {
            const float4* vq = (const float4*)(v1g + ((size_t)b * 10 + cc) * 16);
            float4 b0 = vq[0], b1 = vq[1], b2 = vq[2], b3 = vq[3];
            a0.x += b0.x; a0.y += b0.y; a0.z += b0.z; a0.w += b0.w;
            a1.x += b1.x; a1.y += b1.y; a1.z += b1.z; a1.w += b1.w;
            a2.x += b2.x; a2.y += b2.y; a2.z += b2.z; a2.w += b2.w;
            a3.x += b3.x; a3.y += b3.y; a3.z += b3.z; a3.w += b3.w;
        }
        v[0]=a0.x; v[1]=a0.y; v[2]=a0.z; v[3]=a0.w;
        v[4]=a1.x; v[5]=a1.y; v[6]=a1.z; v[7]=a1.w;
        v[8]=a2.x; v[9]=a2.y; v[10]=a2.z; v[11]=a2.w;
        v[12]=a3.x; v[13]=a3.y; v[14]=a3.z; v[15]=a3.w;
    }

    float sacc[16];
    #pragma unroll
    for (int d = 0; d < 16; ++d) sacc[d] = 0.0f;

    const uint4* up = (const uint4*)uhat_h;   // 8 bf16 per uint4
    // row (b,i) = 160 bf16 = 20 uint4; lane's slice: +c*2 uint4
    size_t base = ((size_t)b * 1152 + i0 + isub) * 20 + (size_t)c * 2;

    #pragma unroll 1
    for (int ii = 0; ii < 72; ii += 4) {
        uint4 h0 = make_uint4(0u,0u,0u,0u), h1 = make_uint4(0u,0u,0u,0u);
        if (act) { h0 = up[base]; h1 = up[base + 1]; }
        base += 80;                        // 4 rows ahead
        float x[16];
        x[0]  = bf16_lo(h0.x); x[1]  = bf16_hi(h0.x);
        x[2]  = bf16_lo(h0.y); x[3]  = bf16_hi(h0.y);
        x[4]  = bf16_lo(h0.z); x[5]  = bf16_hi(h0.z);
        x[6]  = bf16_lo(h0.w); x[7]  = bf16_hi(h0.w);
        x[8]  = bf16_lo(h1.x); x[9]  = bf16_hi(h1.x);
        x[10] = bf16_lo(h1.y); x[11] = bf16_hi(h1.y);
        x[12] = bf16_lo(h1.z); x[13] = bf16_hi(h1.z);
        x[14] = bf16_lo(h1.w); x[15] = bf16_hi(h1.w);
        // lane-local dot, 4 partial chains
        float d0 = x[0]*v[0] + x[4]*v[4] + x[8]*v[8]   + x[12]*v[12];
        float d1 = x[1]*v[1] + x[5]*v[5] + x[9]*v[9]   + x[13]*v[13];
        float d2 = x[2]*v[2] + x[6]*v[6] + x[10]*v[10] + x[14]*v[14];
        float d3 = x[3]*v[3] + x[7]*v[7] + x[11]*v[11] + x[15]*v[15];
        const float logit = (d0 + d1) + (d2 + d3);
        // softmax over c within the 16-lane group (no max-sub: |logit| small)
        const float e = act ? __expf(logit) : 0.0f;
        float ss = e;
        ss += __shfl_xor(ss, 1);
        ss += __shfl_xor(ss, 2);
        ss += __shfl_xor(ss, 4);
        ss += __shfl_xor(ss, 8);
        const float coef = e * __builtin_amdgcn_rcpf(ss);
        #pragma unroll
        for (int d = 0; d < 16; ++d) sacc[d] += coef * x[d];
    }

    // reduce over the 4 i_sub groups: lanes {L, L^16, L^32, L^48}
    #pragma unroll
    for (int d = 0; d < 16; ++d) {
        sacc[d] += __shfl_xor(sacc[d], 16);
        sacc[d] += __shfl_xor(sacc[d], 32);
    }
    if (lane < 10) {
#if defined(__HIP_DEVICE_COMPILE__)
        float* sp = sg + (size_t)b * 160 + c * 16;
        #pragma unroll
        for (int d = 0; d < 16; ++d) unsafeAtomicAdd(sp + d, sacc[d]);
#endif
    }
}

// ---------------- squash with pre-scale ----------------
__global__ void squash_scale(const float* __restrict__ s, float* __restrict__ vout,
                             float scale)
{
    int r = blockIdx.x * 256 + threadIdx.x;
    if (r >= 512 * 10) return;
    const float* sp = s + (size_t)r * 16;
    float sv[16];
    float ns = 0.0f;
    #pragma unroll
    for (int d = 0; d < 16; ++d) {
        float x = sp[d] * scale;
        sv[d] = x;
        ns += x * x;
    }
    float sc = ns / ((1.0f + ns) * (sqrtf(ns) + 1e-8f));
    float* o = vout + (size_t)r * 16;
    #pragma unroll
    for (int d = 0; d < 16; ++d) o[d] = sv[d] * sc;
}

// ---------------- tiny-ws fallback (R3-style): thread owns (b,c) ----------------
template <int PASS>
__global__ __launch_bounds__(256, 4)
void pass_fb(const float* __restrict__ u, const float* __restrict__ W,
             const float* __restrict__ v0g, const float* __restrict__ v1g,
             float* __restrict__ s_atomic)
{
    const int t    = threadIdx.x;
    const int lane = t & 63;
    const int wv   = t >> 6;
    const int bsub = lane / 10;
    const int c    = lane - bsub * 10;
    const bool lane_ok = (bsub < 6);
    const int b    = blockIdx.y * 24 + wv * 6 + bsub;
    const bool valid = lane_ok && (b < 512);
    const int bc   = valid ? b : 511;
    const int base = lane_ok ? bsub * 10 : 0;
    const int i0   = blockIdx.x * 24;

    float v[16];
    #pragma unroll
    for (int d = 0; d < 16; ++d) v[d] = 0.0f;
    if (PASS >= 1) {
        const float* vp = v0g + ((size_t)bc * 10 + c) * 16;
        #pragma unroll
        for (int d = 0; d < 16; ++d) v[d] = vp[d];
        if (PASS >= 2) {
            const float* vq = v1g + ((size_t)bc * 10 + c) * 16;
            #pragma unroll
            for (int d = 0; d < 16; ++d) v[d] += vq[d];
        }
    }

    float s_acc[16];
    #pragma unroll
    for (int d = 0; d < 16; ++d) s_acc[d] = 0.0f;

    for (int ii = 0; ii < 24; ++ii) {
        const int i = i0 + ii;
        const float4* up = (const float4*)(u + ((size_t)bc * 1152 + i) * 8);
        const float4 ua = up[0];
        const float4 ub = up[1];
        const float* Wp = W + ((size_t)i * 10 + c) * 128;

        float h[16];
        #pragma unroll
        for (int d = 0; d < 16; ++d) {
            const float4* wp = (const float4*)(Wp + d * 8);
            h[d] = dot8(wp[0], wp[1], ua, ub);
        }

        if (PASS == 0) {
            #pragma unroll
            for (int d = 0; d < 16; ++d) s_acc[d] += h[d];
        } else {
            float lg = 0.0f;
            #pragma unroll
            for (int d = 0; d < 16; ++d) lg += h[d] * v[d];
            float lj[10];
            #pragma unroll
            for (int j = 0; j < 10; ++j) lj[j] = __shfl(lg, base + j);
            float m = lj[0];
            #pragma unroll
            for (int j = 1; j < 10; ++j) m = fmaxf(m, lj[j]);
            float sum = 0.0f;
            #pragma unroll
            for (int j = 0; j < 10; ++j) sum += __expf(lj[j] - m);
            const float coef = __expf(lg - m) / sum;
            #pragma unroll
            for (int d = 0; d < 16; ++d) s_acc[d] += coef * h[d];
        }
    }
    if (PASS == 0) {
        #pragma unroll
        for (int d = 0; d < 16; ++d) s_acc[d] *= 0.1f;
    }
    if (valid) {
#if defined(__HIP_DEVICE_COMPILE__)
        #pragma unroll
        for (int d = 0; d < 16; ++d)
            unsafeAtomicAdd(&s_atomic[((size_t)b * 10 + c) * 16 + d], s_acc[d]);
#endif
    }
}

extern "C" void kernel_launch(void* const* d_in, const int* in_sizes, int n_in,
                              void* d_out, int out_size, void* d_ws, size_t ws_size,
                              hipStream_t stream)
{
    const float* u = (const float*)d_in[0];   // [512,1152,8]
    const float* W = (const float*)d_in[1];   // [1152,10,16,8]
    float* out = (float*)d_out;               // [512,10,16]

    float* v0 = (float*)d_ws;
    float* v1 = v0 + 81920;
    float* s0 = v1 + 81920;
    float* s1 = s0 + 81920;
    float* s2 = s1 + 81920;
    float* wt = s2 + 81920;                   // 1,474,560 f32 (5.9 MB)

    const size_t head   = (size_t)5 * 81920 * sizeof(float);          // 1.64 MB
    const size_t wtsz   = (size_t)1152 * 1280 * sizeof(float);        // 5.90 MB
    const size_t uh_b16 = (size_t)512 * 1152 * 160 * 2;               // 188.7 MB

    hipMemsetAsync(s0, 0, (size_t)3 * 81920 * sizeof(float), stream);

    dim3 blk(256);

    if (ws_size >= head + wtsz + uh_b16) {
        unsigned short* uhh = (unsigned short*)(wt + 1152 * 1280);
        transpose_W<<<1440, blk, 0, stream>>>((const float4*)W, (float4*)wt);
        produce_uhat_t<<<2048, blk, 0, stream>>>(u, wt, uhh, s0);
        squash_scale<<<20, blk, 0, stream>>>(s0, v0, 0.1f);
        route3<1><<<2048, blk, 0, stream>>>(uhh, v0, nullptr, s1);
        squash_scale<<<20, blk, 0, stream>>>(s1, v1, 1.0f);
        route3<2><<<2048, blk, 0, stream>>>(uhh, v0, v1, s2);
        squash_scale<<<20, blk, 0, stream>>>(s2, out, 1.0f);
    } else if (ws_size >= head + uh_b16) {
        unsigned short* uhh = (unsigned short*)wt;   // no W_t buffer
        produce_uhat_div<<<2048, blk, 0, stream>>>(u, W, uhh, s0);
        squash_scale<<<20, blk, 0, stream>>>(s0, v0, 0.1f);
        route3<1><<<2048, blk, 0, stream>>>(uhh, v0, nullptr, s1);
        squash_scale<<<20, blk, 0, stream>>>(s1, v1, 1.0f);
        route3<2><<<2048, blk, 0, stream>>>(uhh, v0, v1, s2);
        squash_scale<<<20, blk, 0, stream>>>(s2, out, 1.0f);
    } else {
        dim3 grid(48, 22);
        pass_fb<0><<<grid, blk, 0, stream>>>(u, W, nullptr, nullptr, s0);
        squash_scale<<<20, blk, 0, stream>>>(s0, v0, 1.0f);
        pass_fb<1><<<grid, blk, 0, stream>>>(u, W, v0, nullptr, s1);
        squash_scale<<<20, blk, 0, stream>>>(s1, v1, 1.0f);
        pass_fb<2><<<grid, blk, 0, stream>>>(u, W, v0, v1, s2);
        squash_scale<<<20, blk, 0, stream>>>(s2, out, 1.0f);
    }
}

// Round 5
// 328.581 us; speedup vs baseline: 1.3657x; 1.3657x over previous
//
#include <hip/hip_runtime.h>
#include <math.h>

// DigitCaps dynamic routing. B=512, I=1152, K=8, C=10, D=16, 3 iters.
//
// R5 structure: materialize bf16 u_hat (189 MB) in ws; each routing pass
// streams it once; softmax fully in-register.
// R7 POST-MORTEM: forcing launch_bounds(256,6) on producer -> VGPR 40 -> 1.2 GB
//   scratch. Never cap the allocator below the body's natural need.
// R9 = best known (336us): producer K1_CH=32 grid 1024; route2 VGPR~80 grid 1024.
// R10 POST-MORTEM: (a) grid 2048 didn't raise residency (occupancy stuck 38%)
//   and doubled s0 atomics (+30us producer). (b) route3's (256,8) cap = R7
//   repeat: 64-VGPR cap on ~78-reg body -> spills -> 125us/pass.
// R11: restore R9 geometry; add ILP ONLY (registers are free below the 128 cap
//   of (256,4)):
//   - producer: next-ii W_t prefetch (w4n rotate) hides L2/L3 latency under
//     the 400-cyc dot/pack body.
//   - route4: unroll-2 pipeline - two INDEPENDENT row-chains interleaved
//     (halves exposed shfl-butterfly latency) + 2-step-ahead load prefetch.

#define UHQ 40          // ushort4 quads per (b,i) row (160 bf16 elems)
#define K1_CH 32        // producer i-chunks (36 i each), 4 b per wave
#define K2_CH 8         // route i-chunks per b (144 i each)

__device__ __forceinline__ float dot8(const float4 w0, const float4 w1,
                                      const float4 ua, const float4 ub) {
    return w0.x*ua.x + w0.y*ua.y + w0.z*ua.z + w0.w*ua.w
         + w1.x*ub.x + w1.y*ub.y + w1.z*ub.z + w1.w*ub.w;
}

__device__ __forceinline__ unsigned short bf16_rn(float x) {
    unsigned u = __float_as_uint(x);
    u += 0x7FFFu + ((u >> 16) & 1u);
    return (unsigned short)(u >> 16);
}
__device__ __forceinline__ float bf16_lo(unsigned p) {   // low bf16 of packed pair
    return __uint_as_float(p << 16);
}
__device__ __forceinline__ float bf16_hi(unsigned p) {   // high bf16 of packed pair
    return __uint_as_float(p & 0xFFFF0000u);
}

// ---------------- W transpose: W[i][c][d][k] -> W_t[i][j][q] (float4 units) ----------------
__global__ void transpose_W(const float4* __restrict__ W4, float4* __restrict__ Wt4)
{
    int tid = blockIdx.x * 256 + threadIdx.x;
    if (tid >= 1152 * 320) return;
    int i = tid / 320, r = tid - i * 320;
    int q = r >> 3, j = r & 7;
    Wt4[i * 320 + j * 40 + q] = W4[tid];   // read coalesced, scatter within 5 KB row
}

// ---------------- Producer (coalesced W_t): u_hat bf16 + fused pass-0 sum ----------------
// (256,4) -> allocator cap 128 VGPR; body + prefetch ~100. Grid 1024 = 4/CU,
// one round. W_t loads for ii+1 issued before computing ii (ILP latency hide).
__global__ __launch_bounds__(256, 4)
void produce_uhat_t(const float* __restrict__ u, const float* __restrict__ Wt,
                    unsigned short* __restrict__ uhat_h, float* __restrict__ s0)
{
    const int t = threadIdx.x, lane = t & 63, wv = t >> 6;
    const int gid = blockIdx.x * 4 + wv;
    const int bq  = gid / K1_CH;          // 0..127
    const int ch  = gid - bq * K1_CH;     // 0..31
    const int b0  = bq * 4;
    const int i0  = ch * 36;
    const int q   = lane;
    const bool act = (q < UHQ);

    float4 acc[4];
    #pragma unroll
    for (int bb = 0; bb < 4; ++bb) acc[bb] = make_float4(0.f, 0.f, 0.f, 0.f);

    // preload W_t row i0
    float4 w4[8];
    if (act) {
        const float4* wb = (const float4*)(Wt + (size_t)i0 * 1280);
        #pragma unroll
        for (int j = 0; j < 8; ++j) w4[j] = wb[j * 40 + q];
    }

    #pragma unroll 1
    for (int ii = 0; ii < 36; ++ii) {
        const int i = i0 + ii;
        // prefetch next W_t row before consuming the current one
        float4 w4n[8];
        if (act && (ii + 1 < 36)) {
            const float4* wb = (const float4*)(Wt + (size_t)(i + 1) * 1280);
            #pragma unroll
            for (int j = 0; j < 8; ++j) w4n[j] = wb[j * 40 + q];   // 640 B contiguous
        }
        #pragma unroll
        for (int bb = 0; bb < 4; ++bb) {
            const int b = b0 + bb;
            const float4* up = (const float4*)(u + ((size_t)b * 1152 + i) * 8);
            const float4 ua = up[0], ub = up[1];   // wave-uniform broadcast
            if (act) {
                float4 uh;
                uh.x = dot8(w4[0], w4[1], ua, ub);
                uh.y = dot8(w4[2], w4[3], ua, ub);
                uh.z = dot8(w4[4], w4[5], ua, ub);
                uh.w = dot8(w4[6], w4[7], ua, ub);
                acc[bb].x += uh.x; acc[bb].y += uh.y;
                acc[bb].z += uh.z; acc[bb].w += uh.w;
                ushort4 h;
                h.x = bf16_rn(uh.x); h.y = bf16_rn(uh.y);
                h.z = bf16_rn(uh.z); h.w = bf16_rn(uh.w);
                ((ushort4*)uhat_h)[((size_t)b * 1152 + i) * UHQ + q] = h;
            }
        }
        #pragma unroll
        for (int j = 0; j < 8; ++j) w4[j] = w4n[j];
    }
    if (act) {
#if defined(__HIP_DEVICE_COMPILE__)
        #pragma unroll
        for (int bb = 0; bb < 4; ++bb) {
            float* sp = s0 + (size_t)(b0 + bb) * 160 + q * 4;
            unsafeAtomicAdd(sp + 0, acc[bb].x);
            unsafeAtomicAdd(sp + 1, acc[bb].y);
            unsafeAtomicAdd(sp + 2, acc[bb].z);
            unsafeAtomicAdd(sp + 3, acc[bb].w);
        }
#endif
    }
}

// ---------------- Producer fallback (divergent W, no W_t buffer) ----------------
__global__ __launch_bounds__(256, 4)
void produce_uhat_div(const float* __restrict__ u, const float* __restrict__ W,
                      unsigned short* __restrict__ uhat_h, float* __restrict__ s0)
{
    const int t = threadIdx.x, lane = t & 63, wv = t >> 6;
    const int gid = blockIdx.x * 4 + wv;
    const int bq  = gid / K1_CH;
    const int ch  = gid - bq * K1_CH;
    const int b0  = bq * 4;
    const int i0  = ch * 36;
    const int q   = lane;
    const bool act = (q < UHQ);

    float4 acc[4];
    #pragma unroll
    for (int bb = 0; bb < 4; ++bb) acc[bb] = make_float4(0.f, 0.f, 0.f, 0.f);

    for (int ii = 0; ii < 36; ++ii) {
        const int i = i0 + ii;
        float4 w4[8];
        if (act) {
            const float4* wp = (const float4*)(W + (size_t)i * 1280 + q * 32);
            #pragma unroll
            for (int j = 0; j < 8; ++j) w4[j] = wp[j];
        }
        #pragma unroll
        for (int bb = 0; bb < 4; ++bb) {
            const int b = b0 + bb;
            const float4* up = (const float4*)(u + ((size_t)b * 1152 + i) * 8);
            const float4 ua = up[0], ub = up[1];
            if (act) {
                float4 uh;
                uh.x = dot8(w4[0], w4[1], ua, ub);
                uh.y = dot8(w4[2], w4[3], ua, ub);
                uh.z = dot8(w4[4], w4[5], ua, ub);
                uh.w = dot8(w4[6], w4[7], ua, ub);
                acc[bb].x += uh.x; acc[bb].y += uh.y;
                acc[bb].z += uh.z; acc[bb].w += uh.w;
                ushort4 h;
                h.x = bf16_rn(uh.x); h.y = bf16_rn(uh.y);
                h.z = bf16_rn(uh.z); h.w = bf16_rn(uh.w);
                ((ushort4*)uhat_h)[((size_t)b * 1152 + i) * UHQ + q] = h;
            }
        }
    }
    if (act) {
#if defined(__HIP_DEVICE_COMPILE__)
        #pragma unroll
        for (int bb = 0; bb < 4; ++bb) {
            float* sp = s0 + (size_t)(b0 + bb) * 160 + q * 4;
            unsafeAtomicAdd(sp + 0, acc[bb].x);
            unsafeAtomicAdd(sp + 1, acc[bb].y);
            unsafeAtomicAdd(sp + 2, acc[bb].z);
            unsafeAtomicAdd(sp + 3, acc[bb].w);
        }
#endif
    }
}

// ---------------- one routing step: 4 rows (isub groups), softmax over c ----------------
__device__ __forceinline__ void route_step(const uint4 h0, const uint4 h1,
                                           const float* __restrict__ v,
                                           float* __restrict__ sacc, bool act)
{
    float x[16];
    x[0]  = bf16_lo(h0.x); x[1]  = bf16_hi(h0.x);
    x[2]  = bf16_lo(h0.y); x[3]  = bf16_hi(h0.y);
    x[4]  = bf16_lo(h0.z); x[5]  = bf16_hi(h0.z);
    x[6]  = bf16_lo(h0.w); x[7]  = bf16_hi(h0.w);
    x[8]  = bf16_lo(h1.x); x[9]  = bf16_hi(h1.x);
    x[10] = bf16_lo(h1.y); x[11] = bf16_hi(h1.y);
    x[12] = bf16_lo(h1.z); x[13] = bf16_hi(h1.z);
    x[14] = bf16_lo(h1.w); x[15] = bf16_hi(h1.w);
    // lane-local dot over d (4 partial chains)
    float d0 = x[0]*v[0] + x[4]*v[4] + x[8]*v[8]   + x[12]*v[12];
    float d1 = x[1]*v[1] + x[5]*v[5] + x[9]*v[9]   + x[13]*v[13];
    float d2 = x[2]*v[2] + x[6]*v[6] + x[10]*v[10] + x[14]*v[14];
    float d3 = x[3]*v[3] + x[7]*v[7] + x[11]*v[11] + x[15]*v[15];
    const float logit = (d0 + d1) + (d2 + d3);
    // softmax over c inside the 16-lane group (no max-sub: |logit| small)
    const float e = act ? __expf(logit) : 0.0f;
    float ss = e;
    ss += __shfl_xor(ss, 1);
    ss += __shfl_xor(ss, 2);
    ss += __shfl_xor(ss, 4);
    ss += __shfl_xor(ss, 8);
    const float coef = e * __builtin_amdgcn_rcpf(ss);
    #pragma unroll
    for (int d = 0; d < 16; ++d) sacc[d] += coef * x[d];
}

// ---------------- Routing pass v4: unroll-2 pipeline, 2-step prefetch ----------------
// lane = (i_sub 0..3, c 0..15). 36 steps of 4 rows. Two independent step
// chains per iteration interleave their shfl/exp latency; loads for steps
// t+2,t+3 issued before the computes (vmcnt wait lands after them).
// (256,4): allocator cap 128 VGPR; body ~100. NO tighter bound (R7/R10 lesson).
template <int PASS>
__global__ __launch_bounds__(256, 4)
void route4(const unsigned short* __restrict__ uhat_h,
            const float* __restrict__ v0g, const float* __restrict__ v1g,
            float* __restrict__ sg)
{
    const int t = threadIdx.x, lane = t & 63, wv = t >> 6;
    const int gid  = blockIdx.x * 4 + wv;
    const int b    = gid / K2_CH;         // 0..511
    const int ch   = gid - b * K2_CH;     // 0..7
    const int i0   = ch * 144;
    const int isub = lane >> 4;           // 0..3
    const int c    = lane & 15;           // 0..15, valid c<10
    const bool act = (c < 10);
    const int cc   = act ? c : 9;         // clamp for v load

    // v[b, cc, 0..15]  (f32)
    float v[16];
    {
        const float4* vp = (const float4*)(v0g + ((size_t)b * 10 + cc) * 16);
        float4 a0 = vp[0], a1 = vp[1], a2 = vp[2], a3 = vp[3];
        if (PASS == 2) {
            const float4* vq = (const float4*)(v1g + ((size_t)b * 10 + cc) * 16);
            float4 b0 = vq[0], b1 = vq[1], b2 = vq[2], b3 = vq[3];
            a0.x += b0.x; a0.y += b0.y; a0.z += b0.z; a0.w += b0.w;
            a1.x += b1.x; a1.y += b1.y; a1.z += b1.z; a1.w += b1.w;
            a2.x += b2.x; a2.y += b2.y; a2.z += b2.z; a2.w += b2.w;
            a3.x += b3.x; a3.y += b3.y; a3.z += b3.z; a3.w += b3.w;
        }
        v[0]=a0.x; v[1]=a0.y; v[2]=a0.z; v[3]=a0.w;
        v[4]=a1.x; v[5]=a1.y; v[6]=a1.z; v[7]=a1.w;
        v[8]=a2.x; v[9]=a2.y; v[10]=a2.z; v[11]=a2.w;
        v[12]=a3.x; v[13]=a3.y; v[14]=a3.z; v[15]=a3.w;
    }

    float sacc[16];
    #pragma unroll
    for (int d = 0; d < 16; ++d) sacc[d] = 0.0f;

    const uint4* up = (const uint4*)uhat_h;   // 8 bf16 per uint4
    // row (b,i) = 160 bf16 = 20 uint4; lane slice +c*2; step stride = 80 uint4
    size_t base = ((size_t)b * 1152 + i0 + isub) * 20 + (size_t)c * 2;

    // preload steps 0 and 1
    uint4 a0 = make_uint4(0u,0u,0u,0u), a1 = a0, b0 = a0, b1 = a0;
    if (act) {
        a0 = up[base];       a1 = up[base + 1];
        b0 = up[base + 80];  b1 = up[base + 81];
    }
    base += 160;

    #pragma unroll 1
    for (int tt = 0; tt < 36; tt += 2) {
        uint4 nA0 = make_uint4(0u,0u,0u,0u), nA1 = nA0, nB0 = nA0, nB1 = nA0;
        if (act && (tt + 2 < 36)) {
            nA0 = up[base];      nA1 = up[base + 1];
            nB0 = up[base + 80]; nB1 = up[base + 81];
        }
        base += 160;
        route_step(a0, a1, v, sacc, act);   // step tt
        route_step(b0, b1, v, sacc, act);   // step tt+1 (independent chain)
        a0 = nA0; a1 = nA1; b0 = nB0; b1 = nB1;
    }

    // reduce over the 4 i_sub groups: lanes {L, L^16, L^32, L^48}
    #pragma unroll
    for (int d = 0; d < 16; ++d) {
        sacc[d] += __shfl_xor(sacc[d], 16);
        sacc[d] += __shfl_xor(sacc[d], 32);
    }
    if (lane < 10) {
#if defined(__HIP_DEVICE_COMPILE__)
        float* sp = sg + (size_t)b * 160 + c * 16;
        #pragma unroll
        for (int d = 0; d < 16; ++d) unsafeAtomicAdd(sp + d, sacc[d]);
#endif
    }
}

// ---------------- squash with pre-scale ----------------
__global__ void squash_scale(const float* __restrict__ s, float* __restrict__ vout,
                             float scale)
{
    int r = blockIdx.x * 256 + threadIdx.x;
    if (r >= 512 * 10) return;
    const float* sp = s + (size_t)r * 16;
    float sv[16];
    float ns = 0.0f;
    #pragma unroll
    for (int d = 0; d < 16; ++d) {
        float x = sp[d] * scale;
        sv[d] = x;
        ns += x * x;
    }
    float sc = ns / ((1.0f + ns) * (sqrtf(ns) + 1e-8f));
    float* o = vout + (size_t)r * 16;
    #pragma unroll
    for (int d = 0; d < 16; ++d) o[d] = sv[d] * sc;
}

// ---------------- tiny-ws fallback (R3-style): thread owns (b,c) ----------------
template <int PASS>
__global__ __launch_bounds__(256, 4)
void pass_fb(const float* __restrict__ u, const float* __restrict__ W,
             const float* __restrict__ v0g, const float* __restrict__ v1g,
             float* __restrict__ s_atomic)
{
    const int t    = threadIdx.x;
    const int lane = t & 63;
    const int wv   = t >> 6;
    const int bsub = lane / 10;
    const int c    = lane - bsub * 10;
    const bool lane_ok = (bsub < 6);
    const int b    = blockIdx.y * 24 + wv * 6 + bsub;
    const bool valid = lane_ok && (b < 512);
    const int bc   = valid ? b : 511;
    const int base = lane_ok ? bsub * 10 : 0;
    const int i0   = blockIdx.x * 24;

    float v[16];
    #pragma unroll
    for (int d = 0; d < 16; ++d) v[d] = 0.0f;
    if (PASS >= 1) {
        const float* vp = v0g + ((size_t)bc * 10 + c) * 16;
        #pragma unroll
        for (int d = 0; d < 16; ++d) v[d] = vp[d];
        if (PASS >= 2) {
            const float* vq = v1g + ((size_t)bc * 10 + c) * 16;
            #pragma unroll
            for (int d = 0; d < 16; ++d) v[d] += vq[d];
        }
    }

    float s_acc[16];
    #pragma unroll
    for (int d = 0; d < 16; ++d) s_acc[d] = 0.0f;

    for (int ii = 0; ii < 24; ++ii) {
        const int i = i0 + ii;
        const float4* up = (const float4*)(u + ((size_t)bc * 1152 + i) * 8);
        const float4 ua = up[0];
        const float4 ub = up[1];
        const float* Wp = W + ((size_t)i * 10 + c) * 128;

        float h[16];
        #pragma unroll
        for (int d = 0; d < 16; ++d) {
            const float4* wp = (const float4*)(Wp + d * 8);
            h[d] = dot8(wp[0], wp[1], ua, ub);
        }

        if (PASS == 0) {
            #pragma unroll
            for (int d = 0; d < 16; ++d) s_acc[d] += h[d];
        } else {
            float lg = 0.0f;
            #pragma unroll
            for (int d = 0; d < 16; ++d) lg += h[d] * v[d];
            float lj[10];
            #pragma unroll
            for (int j = 0; j < 10; ++j) lj[j] = __shfl(lg, base + j);
            float m = lj[0];
            #pragma unroll
            for (int j = 1; j < 10; ++j) m = fmaxf(m, lj[j]);
            float sum = 0.0f;
            #pragma unroll
            for (int j = 0; j < 10; ++j) sum += __expf(lj[j] - m);
            const float coef = __expf(lg - m) / sum;
            #pragma unroll
            for (int d = 0; d < 16; ++d) s_acc[d] += coef * h[d];
        }
    }
    if (PASS == 0) {
        #pragma unroll
        for (int d = 0; d < 16; ++d) s_acc[d] *= 0.1f;
    }
    if (valid) {
#if defined(__HIP_DEVICE_COMPILE__)
        #pragma unroll
        for (int d = 0; d < 16; ++d)
            unsafeAtomicAdd(&s_atomic[((size_t)b * 10 + c) * 16 + d], s_acc[d]);
#endif
    }
}

extern "C" void kernel_launch(void* const* d_in, const int* in_sizes, int n_in,
                              void* d_out, int out_size, void* d_ws, size_t ws_size,
                              hipStream_t stream)
{
    const float* u = (const float*)d_in[0];   // [512,1152,8]
    const float* W = (const float*)d_in[1];   // [1152,10,16,8]
    float* out = (float*)d_out;               // [512,10,16]

    float* v0 = (float*)d_ws;
    float* v1 = v0 + 81920;
    float* s0 = v1 + 81920;
    float* s1 = s0 + 81920;
    float* s2 = s1 + 81920;
    float* wt = s2 + 81920;                   // 1,474,560 f32 (5.9 MB)

    const size_t head   = (size_t)5 * 81920 * sizeof(float);          // 1.64 MB
    const size_t wtsz   = (size_t)1152 * 1280 * sizeof(float);        // 5.90 MB
    const size_t uh_b16 = (size_t)512 * 1152 * 160 * 2;               // 188.7 MB

    hipMemsetAsync(s0, 0, (size_t)3 * 81920 * sizeof(float), stream);

    dim3 blk(256);

    if (ws_size >= head + wtsz + uh_b16) {
        unsigned short* uhh = (unsigned short*)(wt + 1152 * 1280);
        transpose_W<<<1440, blk, 0, stream>>>((const float4*)W, (float4*)wt);
        produce_uhat_t<<<1024, blk, 0, stream>>>(u, wt, uhh, s0);
        squash_scale<<<20, blk, 0, stream>>>(s0, v0, 0.1f);
        route4<1><<<1024, blk, 0, stream>>>(uhh, v0, nullptr, s1);
        squash_scale<<<20, blk, 0, stream>>>(s1, v1, 1.0f);
        route4<2><<<1024, blk, 0, stream>>>(uhh, v0, v1, s2);
        squash_scale<<<20, blk, 0, stream>>>(s2, out, 1.0f);
    } else if (ws_size >= head + uh_b16) {
        unsigned short* uhh = (unsigned short*)wt;   // no W_t buffer
        produce_uhat_div<<<1024, blk, 0, stream>>>(u, W, uhh, s0);
        squash_scale<<<20, blk, 0, stream>>>(s0, v0, 0.1f);
        route4<1><<<1024, blk, 0, stream>>>(uhh, v0, nullptr, s1);
        squash_scale<<<20, blk, 0, stream>>>(s1, v1, 1.0f);
        route4<2><<<1024, blk, 0, stream>>>(uhh, v0, v1, s2);
        squash_scale<<<20, blk, 0, stream>>>(s2, out, 1.0f);
    } else {
        dim3 grid(48, 22);
        pass_fb<0><<<grid, blk, 0, stream>>>(u, W, nullptr, nullptr, s0);
        squash_scale<<<20, blk, 0, stream>>>(s0, v0, 1.0f);
        pass_fb<1><<<grid, blk, 0, stream>>>(u, W, v0, nullptr, s1);
        squash_scale<<<20, blk, 0, stream>>>(s1, v1, 1.0f);
        pass_fb<2><<<grid, blk, 0, stream>>>(u, W, v0, v1, s2);
        squash_scale<<<20, blk, 0, stream>>>(s2, out, 1.0f);
    }
}